// Round 1
// baseline (907.571 us; speedup 1.0000x reference)
//
#include <hip/hip_runtime.h>
#include <hip/hip_bf16.h>
#include <stdint.h>

#define NROWS 16384
#define DHALF 384
#define DFULL 768
#define EPSF  1e-8f

typedef __attribute__((ext_vector_type(8))) short  short8;
typedef __attribute__((ext_vector_type(4))) float  f32x4;

// ---- async global->LDS, 16B per lane (wave-uniform base + lane*16) ----
__device__ __forceinline__ void async_copy16(const void* gptr, void* lptr) {
    __builtin_amdgcn_global_load_lds(
        (const __attribute__((address_space(1))) unsigned int*)gptr,
        (__attribute__((address_space(3))) unsigned int*)lptr,
        16, 0, 0);
}

// ---------------------------------------------------------------------
// Kernel 0: zero best[] (argmax accumulator) and out[0]
// ---------------------------------------------------------------------
__global__ void init_kernel(unsigned long long* __restrict__ best,
                            float* __restrict__ out) {
    int i = blockIdx.x * blockDim.x + threadIdx.x;
    if (i < NROWS) best[i] = 0ull;
    if (i == 0) out[0] = 0.0f;
}

// ---------------------------------------------------------------------
// Kernel 1: per-row L2 norm over concat(a,b); write bf16 normalized rows
// one wave per row, 4 waves per block
// ---------------------------------------------------------------------
__global__ __launch_bounds__(256) void normalize_kernel(
    const float* __restrict__ a, const float* __restrict__ b,
    __hip_bfloat16* __restrict__ xb, float* __restrict__ invn) {
    int wave = threadIdx.x >> 6;
    int lane = threadIdx.x & 63;
    int row  = blockIdx.x * 4 + wave;

    const float* pa = a + (size_t)row * DHALF;
    const float* pb = b + (size_t)row * DHALF;

    float va[6], vb[6];
    float s = 0.0f;
#pragma unroll
    for (int it = 0; it < 6; ++it) { va[it] = pa[lane + 64 * it]; s += va[it] * va[it]; }
#pragma unroll
    for (int it = 0; it < 6; ++it) { vb[it] = pb[lane + 64 * it]; s += vb[it] * vb[it]; }
#pragma unroll
    for (int d = 1; d < 64; d <<= 1) s += __shfl_xor(s, d, 64);

    float inv = 1.0f / fmaxf(sqrtf(s), EPSF);
    if (lane == 0) invn[row] = inv;

    __hip_bfloat16* px = xb + (size_t)row * DFULL;
#pragma unroll
    for (int it = 0; it < 6; ++it) px[lane + 64 * it]          = __float2bfloat16(va[it] * inv);
#pragma unroll
    for (int it = 0; it < 6; ++it) px[DHALF + lane + 64 * it]  = __float2bfloat16(vb[it] * inv);
}

// ---------------------------------------------------------------------
// Kernel 2: dots = X*X^T (bf16 MFMA, 128x128 tile, BK=32), row-max+argmax
// with diagonal masked to -1; merge via packed atomicMax per row.
// ---------------------------------------------------------------------
__global__ __launch_bounds__(256) void argmax_kernel(
    const __hip_bfloat16* __restrict__ xbh,
    unsigned long long* __restrict__ best) {
    __shared__ short As[128 * 32];
    __shared__ short Bs[128 * 32];

    const short* xg = (const short*)xbh;

    int rb = blockIdx.x >> 7;
    int cb = blockIdx.x & 127;
    int r0 = rb * 128, c0 = cb * 128;

    int tid  = threadIdx.x;
    int wave = tid >> 6, lane = tid & 63;
    int wr = wave >> 1, wc = wave & 1;
    int quad = lane >> 4, l15 = lane & 15;

    f32x4 acc[4][4] = {};

    int srow = (lane >> 2);        // 0..15 within a 16-row chunk
    int skk  = (lane & 3) * 8;     // 0,8,16,24 shorts (16B granules)

    for (int k0 = 0; k0 < DFULL; k0 += 32) {
        // stage A (rows r0..r0+127) and B (rows c0..c0+127), [128][32] bf16 row-major
#pragma unroll
        for (int c = 0; c < 2; ++c) {
            int chunk = wave * 2 + c;          // 0..7
            int row = chunk * 16 + srow;       // 0..127
            const short* ga = xg + (size_t)(r0 + row) * DFULL + k0 + skk;
            const short* gb = xg + (size_t)(c0 + row) * DFULL + k0 + skk;
            async_copy16(ga, &As[row * 32 + skk]);
            async_copy16(gb, &Bs[row * 32 + skk]);
        }
        __syncthreads();

        short8 af[4], bf[4];
#pragma unroll
        for (int t = 0; t < 4; ++t)
            af[t] = *(const short8*)&As[(wr * 64 + t * 16 + l15) * 32 + quad * 8];
#pragma unroll
        for (int t = 0; t < 4; ++t)
            bf[t] = *(const short8*)&Bs[(wc * 64 + t * 16 + l15) * 32 + quad * 8];

#pragma unroll
        for (int ti = 0; ti < 4; ++ti)
#pragma unroll
            for (int tj = 0; tj < 4; ++tj)
                acc[ti][tj] = __builtin_amdgcn_mfma_f32_16x16x32_bf16(
                    af[ti], bf[tj], acc[ti][tj], 0, 0, 0);
        __syncthreads();
    }

    // Epilogue: per-row max+argmax over this block's 128 columns (per wave: 64 cols)
    int rbase = r0 + wr * 64, cbase = c0 + wc * 64;
#pragma unroll
    for (int ti = 0; ti < 4; ++ti) {
#pragma unroll
        for (int reg = 0; reg < 4; ++reg) {
            int grow = rbase + ti * 16 + quad * 4 + reg;
            float bv = -2.0f; int bc = 0;
#pragma unroll
            for (int tj = 0; tj < 4; ++tj) {
                float v   = acc[ti][tj][reg];
                int  gcol = cbase + tj * 16 + l15;
                if (gcol == grow) v = -1.0f;   // diagonal mask
                if (v > bv) { bv = v; bc = gcol; }
            }
            // reduce across the 16 lanes of this quad (same output row)
#pragma unroll
            for (int d = 1; d < 16; d <<= 1) {
                float ov = __shfl_xor(bv, d, 64);
                int   oc = __shfl_xor(bc, d, 64);
                if (ov > bv) { bv = ov; bc = oc; }
            }
            if (l15 == 0) {
                unsigned u = __float_as_uint(bv);
                u = (u & 0x80000000u) ? ~u : (u | 0x80000000u);  // monotone key
                unsigned long long key =
                    ((unsigned long long)u << 32) | (unsigned)bc;
                atomicMax(&best[grow], key);
            }
        }
    }
}

// ---------------------------------------------------------------------
// Kernel 3: dist_i = ||xn_i - xn_j + eps|| in fp32 from original inputs;
// loss = -mean(log(dist + eps)). One wave per row.
// ---------------------------------------------------------------------
__global__ __launch_bounds__(256) void loss_kernel(
    const float* __restrict__ a, const float* __restrict__ b,
    const float* __restrict__ invn,
    const unsigned long long* __restrict__ best,
    float* __restrict__ out) {
    int wave = threadIdx.x >> 6;
    int lane = threadIdx.x & 63;
    int row  = blockIdx.x * 4 + wave;

    int j = (int)(best[row] & 0xffffffffull);
    float ii = invn[row], ij = invn[j];

    const float* pai = a + (size_t)row * DHALF;
    const float* pbi = b + (size_t)row * DHALF;
    const float* paj = a + (size_t)j * DHALF;
    const float* pbj = b + (size_t)j * DHALF;

    float s = 0.0f;
#pragma unroll
    for (int it = 0; it < 6; ++it) {
        int k = lane + 64 * it;
        float d = pai[k] * ii - paj[k] * ij + EPSF;
        s += d * d;
    }
#pragma unroll
    for (int it = 0; it < 6; ++it) {
        int k = lane + 64 * it;
        float d = pbi[k] * ii - pbj[k] * ij + EPSF;
        s += d * d;
    }
#pragma unroll
    for (int d = 1; d < 64; d <<= 1) s += __shfl_xor(s, d, 64);

    if (lane == 0) {
        float term = -logf(sqrtf(s) + EPSF) * (1.0f / (float)NROWS);
        atomicAdd(out, term);
    }
}

// ---------------------------------------------------------------------
extern "C" void kernel_launch(void* const* d_in, const int* in_sizes, int n_in,
                              void* d_out, int out_size, void* d_ws, size_t ws_size,
                              hipStream_t stream) {
    const float* a = (const float*)d_in[0];
    const float* b = (const float*)d_in[1];
    float* out = (float*)d_out;

    char* ws = (char*)d_ws;
    __hip_bfloat16* xb = (__hip_bfloat16*)ws;                                  // 25165824 B
    unsigned long long* best = (unsigned long long*)(ws + 25165824);           // 131072 B
    float* invn = (float*)(ws + 25165824 + 131072);                            // 65536 B

    init_kernel<<<NROWS / 256, 256, 0, stream>>>(best, out);
    normalize_kernel<<<NROWS / 4, 256, 0, stream>>>(a, b, xb, invn);
    argmax_kernel<<<(NROWS / 128) * (NROWS / 128), 256, 0, stream>>>(xb, best);
    loss_kernel<<<NROWS / 4, 256, 0, stream>>>(a, b, invn, best, out);
}

// Round 2
// 611.294 us; speedup vs baseline: 1.4847x; 1.4847x over previous
//
#include <hip/hip_runtime.h>
#include <hip/hip_bf16.h>
#include <stdint.h>
#include <math.h>

#define NROWS 16384
#define DHALF 384
#define DFULL 768
#define EPSF  1e-8f

typedef __attribute__((ext_vector_type(8))) short  short8;
typedef __attribute__((ext_vector_type(4))) float  f32x4;

// ---- async global->LDS, 16B per lane (wave-uniform base + lane*16) ----
__device__ __forceinline__ void async_copy16(const void* gptr, void* lptr) {
    __builtin_amdgcn_global_load_lds(
        (const __attribute__((address_space(1))) unsigned int*)gptr,
        (__attribute__((address_space(3))) unsigned int*)lptr,
        16, 0, 0);
}

__device__ __forceinline__ unsigned long long pack_key(float v, int idx) {
    unsigned u = __float_as_uint(v);
    u = (u & 0x80000000u) ? ~u : (u | 0x80000000u);  // monotone float->u32
    return ((unsigned long long)u << 32) | (unsigned)idx;
}

// ---------------------------------------------------------------------
// Kernel 0: zero best[] (argmax accumulator) and out[0]
// ---------------------------------------------------------------------
__global__ void init_kernel(unsigned long long* __restrict__ best,
                            float* __restrict__ out) {
    int i = blockIdx.x * blockDim.x + threadIdx.x;
    if (i < NROWS) best[i] = 0ull;
    if (i == 0) out[0] = 0.0f;
}

// ---------------------------------------------------------------------
// Kernel 1: per-row L2 norm over concat(a,b); write bf16 normalized rows
// ---------------------------------------------------------------------
__global__ __launch_bounds__(256) void normalize_kernel(
    const float* __restrict__ a, const float* __restrict__ b,
    __hip_bfloat16* __restrict__ xb, float* __restrict__ invn) {
    int wave = threadIdx.x >> 6;
    int lane = threadIdx.x & 63;
    int row  = blockIdx.x * 4 + wave;

    const float* pa = a + (size_t)row * DHALF;
    const float* pb = b + (size_t)row * DHALF;

    float va[6], vb[6];
    float s = 0.0f;
#pragma unroll
    for (int it = 0; it < 6; ++it) { va[it] = pa[lane + 64 * it]; s += va[it] * va[it]; }
#pragma unroll
    for (int it = 0; it < 6; ++it) { vb[it] = pb[lane + 64 * it]; s += vb[it] * vb[it]; }
#pragma unroll
    for (int d = 1; d < 64; d <<= 1) s += __shfl_xor(s, d, 64);

    float inv = 1.0f / fmaxf(sqrtf(s), EPSF);
    if (lane == 0) invn[row] = inv;

    __hip_bfloat16* px = xb + (size_t)row * DFULL;
#pragma unroll
    for (int it = 0; it < 6; ++it) px[lane + 64 * it]          = __float2bfloat16(va[it] * inv);
#pragma unroll
    for (int it = 0; it < 6; ++it) px[DHALF + lane + 64 * it]  = __float2bfloat16(vb[it] * inv);
}

// ---------------------------------------------------------------------
// Kernel 2: dots = X*X^T, upper-triangle tile-blocks only (symmetry),
// 128x128 tile, BK=32, XOR-swizzled LDS (conflict-free ds_read_b128).
// Row-direction argmax always; col-direction argmax for off-diag blocks.
// ---------------------------------------------------------------------
__global__ __launch_bounds__(256) void argmax_kernel(
    const __hip_bfloat16* __restrict__ xbh,
    unsigned long long* __restrict__ best) {
    __shared__ short As[128 * 32];
    __shared__ short Bs[128 * 32];

    const short* xg = (const short*)xbh;

    // decode upper-triangle pair: k -> (rb <= cb)
    int k = blockIdx.x;
    int i = (int)((sqrtf(8.0f * (float)k + 1.0f) - 1.0f) * 0.5f);
    while ((i + 1) * (i + 2) / 2 <= k) ++i;
    while (i * (i + 1) / 2 > k) --i;
    int cb = i;
    int rb = k - i * (i + 1) / 2;   // rb <= cb
    int r0 = rb * 128, c0 = cb * 128;

    int tid  = threadIdx.x;
    int wave = tid >> 6, lane = tid & 63;
    int wr = wave >> 1, wc = wave & 1;
    int quad = lane >> 4, l15 = lane & 15;

    f32x4 acc[4][4] = {};

    int srow = (lane >> 2);                              // row within 16-row chunk
    int slot = (lane & 3) * 8;                           // LDS granule slot (shorts)
    int gsrc = ((lane & 3) ^ ((lane >> 3) & 3)) * 8;     // swizzled source granule

    for (int k0 = 0; k0 < DFULL; k0 += 32) {
#pragma unroll
        for (int c = 0; c < 2; ++c) {
            int chunk = wave * 2 + c;          // 0..7
            int row = chunk * 16 + srow;       // 0..127
            const short* ga = xg + (size_t)(r0 + row) * DFULL + k0 + gsrc;
            const short* gb = xg + (size_t)(c0 + row) * DFULL + k0 + gsrc;
            async_copy16(ga, &As[row * 32 + slot]);
            async_copy16(gb, &Bs[row * 32 + slot]);
        }
        __syncthreads();

        int sw = (l15 >> 1) & 3;               // row-keyed granule swizzle
        int gq = (quad ^ sw) * 8;
        short8 af[4], bf[4];
#pragma unroll
        for (int t = 0; t < 4; ++t)
            af[t] = *(const short8*)&As[(wr * 64 + t * 16 + l15) * 32 + gq];
#pragma unroll
        for (int t = 0; t < 4; ++t)
            bf[t] = *(const short8*)&Bs[(wc * 64 + t * 16 + l15) * 32 + gq];

#pragma unroll
        for (int ti = 0; ti < 4; ++ti)
#pragma unroll
            for (int tj = 0; tj < 4; ++tj)
                acc[ti][tj] = __builtin_amdgcn_mfma_f32_16x16x32_bf16(
                    af[ti], bf[tj], acc[ti][tj], 0, 0, 0);
        __syncthreads();
    }

    int rbase = r0 + wr * 64, cbase = c0 + wc * 64;

    // Row-direction: best over this block's 128 columns, diag masked
#pragma unroll
    for (int ti = 0; ti < 4; ++ti) {
#pragma unroll
        for (int reg = 0; reg < 4; ++reg) {
            int grow = rbase + ti * 16 + quad * 4 + reg;
            float bv = -2.0f; int bc = 0;
#pragma unroll
            for (int tj = 0; tj < 4; ++tj) {
                float v   = acc[ti][tj][reg];
                int  gcol = cbase + tj * 16 + l15;
                if (gcol == grow) v = -1.0f;   // diagonal mask
                if (v > bv) { bv = v; bc = gcol; }
            }
#pragma unroll
            for (int d = 1; d < 16; d <<= 1) {
                float ov = __shfl_xor(bv, d, 64);
                int   oc = __shfl_xor(bc, d, 64);
                if (ov > bv) { bv = ov; bc = oc; }
            }
            if (l15 == 0) atomicMax(&best[grow], pack_key(bv, bc));
        }
    }

    // Column-direction (off-diagonal blocks): best over this block's 128 rows
    if (rb != cb) {
#pragma unroll
        for (int tj = 0; tj < 4; ++tj) {
            float bv = -2.0f; int br = 0;
#pragma unroll
            for (int ti = 0; ti < 4; ++ti)
#pragma unroll
                for (int reg = 0; reg < 4; ++reg) {
                    float v = acc[ti][tj][reg];
                    int grow = rbase + ti * 16 + quad * 4 + reg;
                    if (v > bv) { bv = v; br = grow; }
                }
#pragma unroll
            for (int d = 16; d < 64; d <<= 1) {
                float ov = __shfl_xor(bv, d, 64);
                int   orr = __shfl_xor(br, d, 64);
                if (ov > bv) { bv = ov; br = orr; }
            }
            if (quad == 0) {
                int gcol = cbase + tj * 16 + l15;
                atomicMax(&best[gcol], pack_key(bv, br));
            }
        }
    }
}

// ---------------------------------------------------------------------
// Kernel 3: dist_i = ||xn_i - xn_j + eps|| in fp32 from original inputs;
// loss = -mean(log(dist + eps)). One wave per row.
// ---------------------------------------------------------------------
__global__ __launch_bounds__(256) void loss_kernel(
    const float* __restrict__ a, const float* __restrict__ b,
    const float* __restrict__ invn,
    const unsigned long long* __restrict__ best,
    float* __restrict__ out) {
    int wave = threadIdx.x >> 6;
    int lane = threadIdx.x & 63;
    int row  = blockIdx.x * 4 + wave;

    int j = (int)(best[row] & 0xffffffffull);
    float ii = invn[row], ij = invn[j];

    const float* pai = a + (size_t)row * DHALF;
    const float* pbi = b + (size_t)row * DHALF;
    const float* paj = a + (size_t)j * DHALF;
    const float* pbj = b + (size_t)j * DHALF;

    float s = 0.0f;
#pragma unroll
    for (int it = 0; it < 6; ++it) {
        int kk = lane + 64 * it;
        float d = pai[kk] * ii - paj[kk] * ij + EPSF;
        s += d * d;
    }
#pragma unroll
    for (int it = 0; it < 6; ++it) {
        int kk = lane + 64 * it;
        float d = pbi[kk] * ii - pbj[kk] * ij + EPSF;
        s += d * d;
    }
#pragma unroll
    for (int d = 1; d < 64; d <<= 1) s += __shfl_xor(s, d, 64);

    if (lane == 0) {
        float term = -logf(sqrtf(s) + EPSF) * (1.0f / (float)NROWS);
        atomicAdd(out, term);
    }
}

// ---------------------------------------------------------------------
extern "C" void kernel_launch(void* const* d_in, const int* in_sizes, int n_in,
                              void* d_out, int out_size, void* d_ws, size_t ws_size,
                              hipStream_t stream) {
    const float* a = (const float*)d_in[0];
    const float* b = (const float*)d_in[1];
    float* out = (float*)d_out;

    char* ws = (char*)d_ws;
    __hip_bfloat16* xb = (__hip_bfloat16*)ws;                                  // 25165824 B
    unsigned long long* best = (unsigned long long*)(ws + 25165824);           // 131072 B
    float* invn = (float*)(ws + 25165824 + 131072);                            // 65536 B

    const int NTILE = NROWS / 128;                     // 128
    const int NBLK  = NTILE * (NTILE + 1) / 2;         // 8256

    init_kernel<<<NROWS / 256, 256, 0, stream>>>(best, out);
    normalize_kernel<<<NROWS / 4, 256, 0, stream>>>(a, b, xb, invn);
    argmax_kernel<<<NBLK, 256, 0, stream>>>(xb, best);
    loss_kernel<<<NROWS / 4, 256, 0, stream>>>(a, b, invn, best, out);
}

// Round 3
// 418.530 us; speedup vs baseline: 2.1685x; 1.4606x over previous
//
#include <hip/hip_runtime.h>
#include <hip/hip_bf16.h>
#include <stdint.h>
#include <math.h>

#define NROWS 16384
#define DHALF 384
#define DFULL 768
#define EPSF  1e-8f

typedef __attribute__((ext_vector_type(8))) short  short8;
typedef __attribute__((ext_vector_type(4))) float  f32x4;

// ---- async global->LDS, 16B per lane (wave-uniform base + lane*16) ----
__device__ __forceinline__ void async_copy16(const void* gptr, void* lptr) {
    __builtin_amdgcn_global_load_lds(
        (const __attribute__((address_space(1))) unsigned int*)gptr,
        (__attribute__((address_space(3))) unsigned int*)lptr,
        16, 0, 0);
}

__device__ __forceinline__ unsigned long long pack_key(float v, int idx) {
    unsigned u = __float_as_uint(v);
    u = (u & 0x80000000u) ? ~u : (u | 0x80000000u);  // monotone float->u32
    return ((unsigned long long)u << 32) | (unsigned)idx;
}

// ---------------------------------------------------------------------
// Kernel 0: zero best[] (argmax accumulator)
// ---------------------------------------------------------------------
__global__ void init_kernel(unsigned long long* __restrict__ best) {
    int i = blockIdx.x * blockDim.x + threadIdx.x;
    if (i < NROWS) best[i] = 0ull;   // any valid key (v >= -1) is > 0
}

// ---------------------------------------------------------------------
// Kernel 1: per-row L2 norm over concat(a,b); write bf16 normalized rows
// ---------------------------------------------------------------------
__global__ __launch_bounds__(256) void normalize_kernel(
    const float* __restrict__ a, const float* __restrict__ b,
    __hip_bfloat16* __restrict__ xb, float* __restrict__ invn) {
    int wave = threadIdx.x >> 6;
    int lane = threadIdx.x & 63;
    int row  = blockIdx.x * 4 + wave;

    const float* pa = a + (size_t)row * DHALF;
    const float* pb = b + (size_t)row * DHALF;

    float va[6], vb[6];
    float s = 0.0f;
#pragma unroll
    for (int it = 0; it < 6; ++it) { va[it] = pa[lane + 64 * it]; s += va[it] * va[it]; }
#pragma unroll
    for (int it = 0; it < 6; ++it) { vb[it] = pb[lane + 64 * it]; s += vb[it] * vb[it]; }
#pragma unroll
    for (int d = 1; d < 64; d <<= 1) s += __shfl_xor(s, d, 64);

    float inv = 1.0f / fmaxf(sqrtf(s), EPSF);
    if (lane == 0) invn[row] = inv;

    __hip_bfloat16* px = xb + (size_t)row * DFULL;
#pragma unroll
    for (int it = 0; it < 6; ++it) px[lane + 64 * it]          = __float2bfloat16(va[it] * inv);
#pragma unroll
    for (int it = 0; it < 6; ++it) px[DHALF + lane + 64 * it]  = __float2bfloat16(vb[it] * inv);
}

// ---------------------------------------------------------------------
// Kernel 2: dots = X*X^T, upper-triangle tile-blocks only (symmetry),
// 128x128 tile, BK=32, XOR-swizzled LDS (conflict-free ds_read_b128).
// Row-direction argmax always; col-direction argmax for off-diag blocks.
// ---------------------------------------------------------------------
__global__ __launch_bounds__(256) void argmax_kernel(
    const __hip_bfloat16* __restrict__ xbh,
    unsigned long long* __restrict__ best) {
    __shared__ short As[128 * 32];
    __shared__ short Bs[128 * 32];

    const short* xg = (const short*)xbh;

    // decode upper-triangle pair: k -> (rb <= cb)
    int k = blockIdx.x;
    int i = (int)((sqrtf(8.0f * (float)k + 1.0f) - 1.0f) * 0.5f);
    while ((i + 1) * (i + 2) / 2 <= k) ++i;
    while (i * (i + 1) / 2 > k) --i;
    int cb = i;
    int rb = k - i * (i + 1) / 2;   // rb <= cb
    int r0 = rb * 128, c0 = cb * 128;

    int tid  = threadIdx.x;
    int wave = tid >> 6, lane = tid & 63;
    int wr = wave >> 1, wc = wave & 1;
    int quad = lane >> 4, l15 = lane & 15;

    f32x4 acc[4][4] = {};

    int srow = (lane >> 2);                              // row within 16-row chunk
    int slot = (lane & 3) * 8;                           // LDS granule slot (shorts)
    int gsrc = ((lane & 3) ^ ((lane >> 3) & 3)) * 8;     // swizzled source granule

    for (int k0 = 0; k0 < DFULL; k0 += 32) {
#pragma unroll
        for (int c = 0; c < 2; ++c) {
            int chunk = wave * 2 + c;          // 0..7
            int row = chunk * 16 + srow;       // 0..127
            const short* ga = xg + (size_t)(r0 + row) * DFULL + k0 + gsrc;
            const short* gb = xg + (size_t)(c0 + row) * DFULL + k0 + gsrc;
            async_copy16(ga, &As[row * 32 + slot]);
            async_copy16(gb, &Bs[row * 32 + slot]);
        }
        __syncthreads();

        int sw = (l15 >> 1) & 3;               // row-keyed granule swizzle
        int gq = (quad ^ sw) * 8;
        short8 af[4], bf[4];
#pragma unroll
        for (int t = 0; t < 4; ++t)
            af[t] = *(const short8*)&As[(wr * 64 + t * 16 + l15) * 32 + gq];
#pragma unroll
        for (int t = 0; t < 4; ++t)
            bf[t] = *(const short8*)&Bs[(wc * 64 + t * 16 + l15) * 32 + gq];

#pragma unroll
        for (int ti = 0; ti < 4; ++ti)
#pragma unroll
            for (int tj = 0; tj < 4; ++tj)
                acc[ti][tj] = __builtin_amdgcn_mfma_f32_16x16x32_bf16(
                    af[ti], bf[tj], acc[ti][tj], 0, 0, 0);
        __syncthreads();
    }

    int rbase = r0 + wr * 64, cbase = c0 + wc * 64;

    // Row-direction: best over this block's 128 columns, diag masked
#pragma unroll
    for (int ti = 0; ti < 4; ++ti) {
#pragma unroll
        for (int reg = 0; reg < 4; ++reg) {
            int grow = rbase + ti * 16 + quad * 4 + reg;
            float bv = -2.0f; int bc = 0;
#pragma unroll
            for (int tj = 0; tj < 4; ++tj) {
                float v   = acc[ti][tj][reg];
                int  gcol = cbase + tj * 16 + l15;
                if (gcol == grow) v = -1.0f;   // diagonal mask
                if (v > bv) { bv = v; bc = gcol; }
            }
#pragma unroll
            for (int d = 1; d < 16; d <<= 1) {
                float ov = __shfl_xor(bv, d, 64);
                int   oc = __shfl_xor(bc, d, 64);
                if (ov > bv) { bv = ov; bc = oc; }
            }
            if (l15 == 0) atomicMax(&best[grow], pack_key(bv, bc));
        }
    }

    // Column-direction (off-diagonal blocks): best over this block's 128 rows
    if (rb != cb) {
#pragma unroll
        for (int tj = 0; tj < 4; ++tj) {
            float bv = -2.0f; int br = 0;
#pragma unroll
            for (int ti = 0; ti < 4; ++ti)
#pragma unroll
                for (int reg = 0; reg < 4; ++reg) {
                    float v = acc[ti][tj][reg];
                    int grow = rbase + ti * 16 + quad * 4 + reg;
                    if (v > bv) { bv = v; br = grow; }
                }
#pragma unroll
            for (int d = 16; d < 64; d <<= 1) {
                float ov = __shfl_xor(bv, d, 64);
                int   orr = __shfl_xor(br, d, 64);
                if (ov > bv) { bv = ov; br = orr; }
            }
            if (quad == 0) {
                int gcol = cbase + tj * 16 + l15;
                atomicMax(&best[gcol], pack_key(bv, br));
            }
        }
    }
}

// ---------------------------------------------------------------------
// Kernel 3: per-row term = log(||xn_i - xn_j + eps|| + eps), fp32 from
// original inputs. One wave per row. NO atomics — coalesced store.
// ---------------------------------------------------------------------
__global__ __launch_bounds__(256) void loss_kernel(
    const float* __restrict__ a, const float* __restrict__ b,
    const float* __restrict__ invn,
    const unsigned long long* __restrict__ best,
    float* __restrict__ terms) {
    int wave = threadIdx.x >> 6;
    int lane = threadIdx.x & 63;
    int row  = blockIdx.x * 4 + wave;

    int j = (int)(best[row] & 0xffffffffull);
    float ii = invn[row], ij = invn[j];

    const float* pai = a + (size_t)row * DHALF;
    const float* pbi = b + (size_t)row * DHALF;
    const float* paj = a + (size_t)j * DHALF;
    const float* pbj = b + (size_t)j * DHALF;

    float s = 0.0f;
#pragma unroll
    for (int it = 0; it < 6; ++it) {
        int kk = lane + 64 * it;
        float d = pai[kk] * ii - paj[kk] * ij + EPSF;
        s += d * d;
    }
#pragma unroll
    for (int it = 0; it < 6; ++it) {
        int kk = lane + 64 * it;
        float d = pbi[kk] * ii - pbj[kk] * ij + EPSF;
        s += d * d;
    }
#pragma unroll
    for (int d = 1; d < 64; d <<= 1) s += __shfl_xor(s, d, 64);

    if (lane == 0) terms[row] = logf(sqrtf(s) + EPSF);
}

// ---------------------------------------------------------------------
// Kernel 4: single-block tree reduction of terms -> out[0] = -mean
// ---------------------------------------------------------------------
__global__ __launch_bounds__(1024) void reduce_kernel(
    const float* __restrict__ terms, float* __restrict__ out) {
    __shared__ float partial[16];
    int tid = threadIdx.x;
    float s = 0.0f;
#pragma unroll
    for (int it = 0; it < NROWS / 1024; ++it) s += terms[tid + 1024 * it];
#pragma unroll
    for (int d = 1; d < 64; d <<= 1) s += __shfl_xor(s, d, 64);
    if ((tid & 63) == 0) partial[tid >> 6] = s;
    __syncthreads();
    if (tid < 16) {
        s = partial[tid];
#pragma unroll
        for (int d = 1; d < 16; d <<= 1) s += __shfl_xor(s, d, 16);
        if (tid == 0) out[0] = -s * (1.0f / (float)NROWS);
    }
}

// ---------------------------------------------------------------------
extern "C" void kernel_launch(void* const* d_in, const int* in_sizes, int n_in,
                              void* d_out, int out_size, void* d_ws, size_t ws_size,
                              hipStream_t stream) {
    const float* a = (const float*)d_in[0];
    const float* b = (const float*)d_in[1];
    float* out = (float*)d_out;

    char* ws = (char*)d_ws;
    __hip_bfloat16* xb = (__hip_bfloat16*)ws;                                  // 25165824 B
    unsigned long long* best = (unsigned long long*)(ws + 25165824);           // 131072 B
    float* invn  = (float*)(ws + 25165824 + 131072);                           // 65536 B
    float* terms = (float*)(ws + 25165824 + 131072 + 65536);                   // 65536 B

    const int NTILE = NROWS / 128;                     // 128
    const int NBLK  = NTILE * (NTILE + 1) / 2;         // 8256

    init_kernel<<<NROWS / 256, 256, 0, stream>>>(best);
    normalize_kernel<<<NROWS / 4, 256, 0, stream>>>(a, b, xb, invn);
    argmax_kernel<<<NBLK, 256, 0, stream>>>(xb, best);
    loss_kernel<<<NROWS / 4, 256, 0, stream>>>(a, b, invn, best, terms);
    reduce_kernel<<<1, 1024, 0, stream>>>(terms, out);
}